// Round 1
// baseline (59.176 us; speedup 1.0000x reference)
//
#include <hip/hip_runtime.h>

// B=16384, K=32, D=128, N_ENT=100000, N_REL=64
// inputs: 0 user_emb f32[B,D], 1 entity_ids i32[B], 2 neigh_ent_ids i32[B,K],
//         3 neigh_rel_ids i32[B,K], 4 entity_table f32[N_ENT,D],
//         5 relation_table f32[N_REL,D], 6 W f32[D,D]
// out: f32[B,D]

#define BB 16384
#define KK 32
#define DD 128
#define NREL 64

// Mt[d][r] = sum_e rel[r,e] * W[e,d]   (i.e. (rel @ W)^T), 128x64 floats = 32KB
__global__ void kgnn_precompute_mt(const float* __restrict__ rel,
                                   const float* __restrict__ W,
                                   float* __restrict__ Mt) {
    const int r = blockIdx.x;   // 0..63
    const int d = threadIdx.x;  // 0..127
    float acc = 0.f;
#pragma unroll 8
    for (int e = 0; e < DD; ++e) {
        acc += rel[r * DD + e] * W[e * DD + d];  // rel: scalar-broadcast, W: coalesced
    }
    Mt[d * NREL + r] = acc;
}

__global__ __launch_bounds__(256, 4) void kgnn_main(
    const float* __restrict__ user_emb,
    const int* __restrict__ entity_ids,
    const int* __restrict__ neigh_ent,
    const int* __restrict__ neigh_rel,
    const float* __restrict__ entity_table,
    const float* __restrict__ Mt,
    float* __restrict__ out) {
    __shared__ float m_lds[DD * NREL];   // 32 KB, [d][r]
    __shared__ float u_lds[4][DD];       // 2 KB, per-wave user row

    const int tid = threadIdx.x;

    // stage Mt: 8192 floats via 2048 float4 stores (256 thr x 8)
    {
        const float4* src = (const float4*)Mt;
        float4* dst = (float4*)m_lds;
#pragma unroll
        for (int i = 0; i < 8; ++i) dst[tid + 256 * i] = src[tid + 256 * i];
    }

    const int wave = tid >> 6;
    const int lane = tid & 63;
    const int row = blockIdx.x * 4 + wave;

    // stage this wave's user row (coalesced float2)
    {
        float2 u2 = ((const float2*)(user_emb + row * DD))[lane];
        u_lds[wave][2 * lane] = u2.x;
        u_lds[wave][2 * lane + 1] = u2.y;
    }
    __syncthreads();

    const int k = lane & 31;     // lane's neighbor index
    const int half = lane >> 5;  // lane's dim-half
    const int rid = neigh_rel[row * KK + k];
    const int eid = neigh_ent[row * KK + k];

    // scores[k] = u . M[rid]  (each lane does 64 dims, then xor-32 combine)
    float p = 0.f;
    {
        const float* urow = &u_lds[wave][half * 64];
        const float* mcol = &m_lds[(half * 64) * NREL + rid];
#pragma unroll 8
        for (int d = 0; d < 64; ++d) {
            p = fmaf(urow[d], mcol[d * NREL], p);
        }
    }
    p += __shfl_xor(p, 32);  // now every lane holds the full score for k = lane&31

    // softmax over k (both halves hold identical copies -> xor 1..16 reduces per-half)
    float mx = p;
#pragma unroll
    for (int m = 16; m >= 1; m >>= 1) mx = fmaxf(mx, __shfl_xor(mx, m));
    float w = __expf(p - mx);
    float s = w;
#pragma unroll
    for (int m = 16; m >= 1; m >>= 1) s += __shfl_xor(s, m);
    w /= s;

    // aggregation: each lane owns 2 dims (float2), loop k with broadcast weight/eid
    float2 acc = {0.f, 0.f};
#pragma unroll 4
    for (int kk2 = 0; kk2 < KK; ++kk2) {
        const float wk = __shfl(w, kk2);
        const int ek = __shfl(eid, kk2);
        const float2 e2 = ((const float2*)(entity_table + (long long)ek * DD))[lane];
        acc.x = fmaf(wk, e2.x, acc.x);
        acc.y = fmaf(wk, e2.y, acc.y);
    }

    const int se = entity_ids[row];
    const float2 s2 = ((const float2*)(entity_table + (long long)se * DD))[lane];
    float2 o;
    o.x = fmaxf(0.f, s2.x + acc.x);
    o.y = fmaxf(0.f, s2.y + acc.y);
    ((float2*)(out + (long long)row * DD))[lane] = o;
}

extern "C" void kernel_launch(void* const* d_in, const int* in_sizes, int n_in,
                              void* d_out, int out_size, void* d_ws, size_t ws_size,
                              hipStream_t stream) {
    const float* user_emb = (const float*)d_in[0];
    const int* entity_ids = (const int*)d_in[1];
    const int* neigh_ent = (const int*)d_in[2];
    const int* neigh_rel = (const int*)d_in[3];
    const float* entity_table = (const float*)d_in[4];
    const float* relation_table = (const float*)d_in[5];
    const float* W = (const float*)d_in[6];
    float* out = (float*)d_out;
    float* Mt = (float*)d_ws;  // 32 KB

    kgnn_precompute_mt<<<NREL, DD, 0, stream>>>(relation_table, W, Mt);
    kgnn_main<<<BB / 4, 256, 0, stream>>>(user_emb, entity_ids, neigh_ent,
                                          neigh_rel, entity_table, Mt, out);
}